// Round 4
// baseline (13171.188 us; speedup 1.0000x reference)
//
#include <hip/hip_runtime.h>
#include <hip/hip_bf16.h>
#include <math.h>

// Decoder with attention: V=32000 E=512 H=1024 B=64 S=128 T=65 (NT=64 steps)
#define BATCH 64
#define SRC   128
#define HID   1024
#define EMB   512
#define NT    64
#define G4    4096   // 4H

__device__ __forceinline__ float sigmoidf_(float x){ return 1.0f/(1.0f+expf(-x)); }

// ===================== skinny GEMM (precompute hh_term partials) =====================
template<int AMODE>
__launch_bounds__(256, 2)
__global__ void skinny_gemm(const float* __restrict__ A, int lda,
                            const int* __restrict__ toks, const float* __restrict__ emb,
                            const float* __restrict__ W, int ldw,
                            float* __restrict__ partial, int N, int Kchunk){
  const int nc = blockIdx.x;
  const int kc = blockIdx.y;
  const int kbase = kc * Kchunk;
  const int tid = threadIdx.x;
  __shared__ float As[16][68];
  __shared__ float Bs[16][132];
  const int wave = tid >> 6, lane = tid & 63;
  const int lm = lane & 7, ln = lane >> 3;
  const int nwave = nc*128 + wave*32;
  float acc[8][4] = {};
  const int arow = tid >> 2, akc = (tid & 3) * 4;
  for (int k0 = 0; k0 < Kchunk; k0 += 16){
    int kg = kbase + k0 + akc;
    float4 av;
    if (AMODE == 1){
      if (kg < EMB) av = *(const float4*)(emb + (size_t)toks[arow]*EMB + kg);
      else          av = *(const float4*)(A + (size_t)arow*lda + (kg - EMB));
    } else {
      av = *(const float4*)(A + (size_t)arow*lda + kg);
    }
    As[akc+0][arow]=av.x; As[akc+1][arow]=av.y; As[akc+2][arow]=av.z; As[akc+3][arow]=av.w;
    #pragma unroll
    for (int r = 0; r < 2; ++r){
      int idx = tid + r*256;
      int nrow = idx >> 2, bkc = (idx & 3) * 4;
      float4 wv = *(const float4*)(W + (size_t)(nc*128 + nrow)*ldw + kbase + k0 + bkc);
      Bs[bkc+0][nrow]=wv.x; Bs[bkc+1][nrow]=wv.y; Bs[bkc+2][nrow]=wv.z; Bs[bkc+3][nrow]=wv.w;
    }
    __syncthreads();
    #pragma unroll
    for (int k = 0; k < 16; ++k){
      float4 alo = *(const float4*)&As[k][lm*8];
      float4 ahi = *(const float4*)&As[k][lm*8+4];
      float4 b4  = *(const float4*)&Bs[k][wave*32 + ln*4];
      float am[8] = {alo.x,alo.y,alo.z,alo.w,ahi.x,ahi.y,ahi.z,ahi.w};
      float bn[4] = {b4.x,b4.y,b4.z,b4.w};
      #pragma unroll
      for (int i=0;i<8;++i)
        #pragma unroll
        for (int j=0;j<4;++j)
          acc[i][j] += am[i]*bn[j];
    }
    __syncthreads();
  }
  for (int i=0;i<8;++i){
    int m = lm*8+i;
    float4 v = make_float4(acc[i][0],acc[i][1],acc[i][2],acc[i][3]);
    *(float4*)(partial + ((size_t)(kc*64 + m))*N + nwave + ln*4) = v;
  }
}

// ===================== big GEMM 128x128 (precompute enc_proj / encW) =====================
__launch_bounds__(256, 2)
__global__ void big_gemm128(const float* __restrict__ A, int lda,
                            const float* __restrict__ W, int ldw,
                            float* __restrict__ C, int N, int K){
  const int n0 = blockIdx.x * 128;
  const int m0 = blockIdx.y * 128;
  const int tid = threadIdx.x;
  __shared__ float As[16][132];
  __shared__ float Bs[16][132];
  const int wave = tid >> 6, lane = tid & 63;
  const int wm = wave >> 1, wn = wave & 1;
  const int lm = lane & 7, ln = lane >> 3;
  float acc[8][8] = {};
  for (int k0 = 0; k0 < K; k0 += 16){
    #pragma unroll
    for (int r = 0; r < 2; ++r){
      int idx = tid + r*256;
      int row = idx >> 2, kq = (idx & 3) * 4;
      float4 av = *(const float4*)(A + (size_t)(m0+row)*lda + k0 + kq);
      As[kq+0][row]=av.x; As[kq+1][row]=av.y; As[kq+2][row]=av.z; As[kq+3][row]=av.w;
      float4 wv = *(const float4*)(W + (size_t)(n0+row)*ldw + k0 + kq);
      Bs[kq+0][row]=wv.x; Bs[kq+1][row]=wv.y; Bs[kq+2][row]=wv.z; Bs[kq+3][row]=wv.w;
    }
    __syncthreads();
    #pragma unroll
    for (int k = 0; k < 16; ++k){
      float4 a0 = *(const float4*)&As[k][wm*64 + lm*8];
      float4 a1 = *(const float4*)&As[k][wm*64 + lm*8 + 4];
      float4 b0 = *(const float4*)&Bs[k][wn*64 + ln*8];
      float4 b1 = *(const float4*)&Bs[k][wn*64 + ln*8 + 4];
      float am[8] = {a0.x,a0.y,a0.z,a0.w,a1.x,a1.y,a1.z,a1.w};
      float bn[8] = {b0.x,b0.y,b0.z,b0.w,b1.x,b1.y,b1.z,b1.w};
      #pragma unroll
      for (int i=0;i<8;++i)
        #pragma unroll
        for (int j=0;j<8;++j)
          acc[i][j] += am[i]*bn[j];
    }
    __syncthreads();
  }
  for (int i=0;i<8;++i){
    int m = m0 + wm*64 + lm*8 + i;
    float* cp = C + (size_t)m*N + n0 + wn*64 + ln*8;
    *(float4*)cp     = make_float4(acc[i][0],acc[i][1],acc[i][2],acc[i][3]);
    *(float4*)(cp+4) = make_float4(acc[i][4],acc[i][5],acc[i][6],acc[i][7]);
  }
}

__global__ void hh_reduce_kernel(const float* __restrict__ partial,
                                 const float* __restrict__ b_ih, const float* __restrict__ b_hh,
                                 float* __restrict__ hh_term){
  int g = blockIdx.x*512 + threadIdx.x;   // 64*4096
  int n = g & 4095;
  int b = g >> 12;
  float s = b_ih[n] + b_hh[n];
  #pragma unroll
  for (int kc=0; kc<8; ++kc) s += partial[((size_t)(kc*64+b))*G4 + n];
  hh_term[g] = s;
}

__global__ void init_kernel(float* __restrict__ Obuf, unsigned* __restrict__ bar){
  int i = blockIdx.x*512 + threadIdx.x;
  if (i < BATCH*HID) Obuf[i] = 0.f;
  if (i < 4) bar[i] = 0u;
}

// ===================== grid-wide barrier (sense via generation counter) =====================
__device__ __forceinline__ void grid_barrier(unsigned* bar, unsigned nblocks){
  __syncthreads();
  if (threadIdx.x == 0){
    __threadfence();
    unsigned g = __hip_atomic_load(&bar[1], __ATOMIC_ACQUIRE, __HIP_MEMORY_SCOPE_AGENT);
    unsigned old = __hip_atomic_fetch_add(&bar[0], 1u, __ATOMIC_ACQ_REL, __HIP_MEMORY_SCOPE_AGENT);
    if (old == nblocks - 1u){
      __hip_atomic_store(&bar[0], 0u, __ATOMIC_RELAXED, __HIP_MEMORY_SCOPE_AGENT);
      __threadfence();
      __hip_atomic_fetch_add(&bar[1], 1u, __ATOMIC_ACQ_REL, __HIP_MEMORY_SCOPE_AGENT);
    } else {
      while (__hip_atomic_load(&bar[1], __ATOMIC_ACQUIRE, __HIP_MEMORY_SCOPE_AGENT) == g)
        __builtin_amdgcn_s_sleep(2);
    }
    __threadfence();
  }
  __syncthreads();
}

// ===================== persistent decoder: all 64 steps, 3 phases/step =====================
// grid 256 blocks x 512 threads; 1 block/CU (LDS-limited). Block blk owns h-cols j0=blk*4..+3
// (16 W_ih rows in LDS) and comb n-cols j0..j0+3 (4 W_comb rows in LDS).
__global__ __launch_bounds__(512, 1)
void decoder_persistent(const int* __restrict__ tgt, const int* __restrict__ enc_mask,
                        const float* __restrict__ dic, const float* __restrict__ emb,
                        const float* __restrict__ W_ih, const float* __restrict__ W_comb,
                        const float* __restrict__ hh_term, const float* __restrict__ enc_proj,
                        const float* __restrict__ encW,
                        float* __restrict__ e_g, float* __restrict__ emax_g, float* __restrict__ esum_g,
                        float* __restrict__ combh, float* __restrict__ hbuf,
                        float* __restrict__ Obuf, float* __restrict__ out,
                        unsigned* __restrict__ bar){
  const int blk = blockIdx.x, tid = threadIdx.x;
  const int wave = tid >> 6, lane = tid & 63;
  const int bg = lane >> 2, rg = lane & 3;     // 16 b-groups x 4 r-groups
  const int j0 = blk * 4;

  __shared__ float Wg[1536*16];      // W_ih slice, [k][rr], rr=jj*4+g -> row g*1024+j0+jj
  __shared__ float Wc[1024*4];       // W_comb h-part slice, [k][j] -> row j0+j
  __shared__ float scratch[8704];    // ybar/h chunk [128][68] k-major; also partial buffers
  __shared__ int   toks[64];
  __shared__ float e_loc[32];
  __shared__ float al_s[SRC];
  __shared__ float redp[512];

  // one-time weight loads (coalesced global, strided LDS ok)
  for (int rr = 0; rr < 16; ++rr){
    int row = (rr & 3) * 1024 + j0 + (rr >> 2);
    for (int k = tid; k < 1536; k += 512) Wg[k*16 + rr] = W_ih[(size_t)row*1536 + k];
  }
  for (int j = 0; j < 4; ++j){
    int n = j0 + j;
    for (int k = tid; k < 1024; k += 512) Wc[k*4 + j] = W_comb[(size_t)n*3072 + k];
  }
  __syncthreads();

  for (int t = 0; t < NT; ++t){
    // ---------------- P1: gates (K=1536 split over 8 waves x 12 chunks) + LSTM -> h -------------
    if (tid < 64) toks[tid] = tgt[t*BATCH + tid];
    __syncthreads();
    float acc[4][4] = {};
    for (int c = 0; c < 12; ++c){
      { // stage ybar chunk k-major [128][68]
        int b = tid & 63, kq = tid >> 6;
        #pragma unroll
        for (int i = 0; i < 4; ++i){
          int kg = c*128 + kq*16 + i*4;
          float4 v;
          if (kg < EMB) v = *(const float4*)(emb + (size_t)toks[b]*EMB + kg);
          else          v = *(const float4*)(Obuf + b*HID + (kg - EMB));
          int kb = kq*16 + i*4;
          scratch[(kb+0)*68 + b] = v.x;
          scratch[(kb+1)*68 + b] = v.y;
          scratch[(kb+2)*68 + b] = v.z;
          scratch[(kb+3)*68 + b] = v.w;
        }
      }
      __syncthreads();
      #pragma unroll
      for (int kk = 0; kk < 16; ++kk){
        int k = wave*16 + kk;                       // wave's k-slice within chunk
        float4 yb = *(const float4*)&scratch[k*68 + bg*4];
        float4 wv = *(const float4*)&Wg[(c*128 + k)*16 + rg*4];
        float ym[4] = {yb.x, yb.y, yb.z, yb.w};
        float wn[4] = {wv.x, wv.y, wv.z, wv.w};
        #pragma unroll
        for (int i = 0; i < 4; ++i)
          #pragma unroll
          for (int j = 0; j < 4; ++j)
            acc[i][j] += ym[i] * wn[j];
      }
      __syncthreads();
    }
    // store wave partials: [w][rr][b]
    #pragma unroll
    for (int i = 0; i < 4; ++i)
      #pragma unroll
      for (int j = 0; j < 4; ++j)
        scratch[wave*1024 + (rg*4 + j)*64 + bg*4 + i] = acc[i][j];
    __syncthreads();
    if (tid < 256){
      int b = tid & 63, jj = tid >> 6;
      float g4[4];
      #pragma unroll
      for (int g = 0; g < 4; ++g){
        float s = hh_term[b*G4 + g*1024 + j0 + jj];
        #pragma unroll
        for (int w = 0; w < 8; ++w) s += scratch[w*1024 + (jj*4 + g)*64 + b];
        g4[g] = s;
      }
      float c_ = sigmoidf_(g4[1]) * dic[b*HID + j0 + jj] + sigmoidf_(g4[0]) * tanhf(g4[2]);
      hbuf[b*HID + j0 + jj] = sigmoidf_(g4[3]) * tanhf(c_);
    }
    grid_barrier(bar, 256);

    // ---------------- P2a: e partials for (b = blk>>2, sg = blk&3) -----------------------------
    {
      const int b = blk >> 2, sg = blk & 3;
      for (int i = tid; i < HID; i += 512) scratch[i] = hbuf[b*HID + i];
      __syncthreads();
      #pragma unroll
      for (int q = 0; q < 4; ++q){
        int s = sg*32 + wave*4 + q;
        const float* ep = enc_proj + ((size_t)(b*SRC + s))*HID;
        float sum = 0.f;
        #pragma unroll
        for (int m = 0; m < 4; ++m){
          float4 v  = *(const float4*)(ep + m*256 + lane*4);
          float4 hv = *(const float4*)&scratch[m*256 + lane*4];
          sum += v.x*hv.x + v.y*hv.y + v.z*hv.z + v.w*hv.w;
        }
        #pragma unroll
        for (int off = 32; off; off >>= 1) sum += __shfl_down(sum, off);
        if (lane == 0) e_loc[wave*4 + q] = sum;
      }
      __syncthreads();
      if (wave == 0){
        int sl = lane & 31;
        int s = sg*32 + sl;
        bool valid = lane < 32;
        bool msk = valid ? (enc_mask[b*SRC + s] != 0) : true;
        float ev = (valid && !msk) ? e_loc[sl] : -1e30f;
        if (valid) e_g[b*SRC + s] = ev;
        float mv = ev;
        #pragma unroll
        for (int off = 32; off; off >>= 1) mv = fmaxf(mv, __shfl_down(mv, off));
        mv = __shfl(mv, 0);
        float p = (valid && !msk) ? expf(ev - mv) : 0.f;
        float ps = p;
        #pragma unroll
        for (int off = 32; off; off >>= 1) ps += __shfl_down(ps, off);
        if (lane == 0){ emax_g[b*4 + sg] = mv; esum_g[b*4 + sg] = ps; }
      }
      __syncthreads();
    }
    // ---------------- P2b: comb_h for n-cols j0..j0+3, all b (K=1024, 8 chunks) ----------------
    {
      float acc2[4] = {0.f, 0.f, 0.f, 0.f};
      for (int c = 0; c < 8; ++c){
        { // stage h chunk k-major
          int b = tid & 63, kq = tid >> 6;
          #pragma unroll
          for (int i = 0; i < 4; ++i){
            int kg = c*128 + kq*16 + i*4;
            float4 v = *(const float4*)(hbuf + b*HID + kg);
            int kb = kq*16 + i*4;
            scratch[(kb+0)*68 + b] = v.x;
            scratch[(kb+1)*68 + b] = v.y;
            scratch[(kb+2)*68 + b] = v.z;
            scratch[(kb+3)*68 + b] = v.w;
          }
        }
        __syncthreads();
        #pragma unroll
        for (int kk = 0; kk < 16; ++kk){
          int k = wave*16 + kk;
          float4 hb = *(const float4*)&scratch[k*68 + bg*4];
          float w  = Wc[(c*128 + k)*4 + rg];
          acc2[0] += hb.x * w; acc2[1] += hb.y * w;
          acc2[2] += hb.z * w; acc2[3] += hb.w * w;
        }
        __syncthreads();
      }
      // partials [w][ng=rg][b]
      #pragma unroll
      for (int i = 0; i < 4; ++i)
        scratch[wave*256 + rg*64 + bg*4 + i] = acc2[i];
      __syncthreads();
      if (tid < 256){
        int b = tid & 63, j = tid >> 6;
        float s = 0.f;
        #pragma unroll
        for (int w = 0; w < 8; ++w) s += scratch[w*256 + j*64 + b];
        combh[b*HID + j0 + j] = s;
      }
    }
    grid_barrier(bar, 256);

    // ---------------- P3: softmax + comb_a + tanh + write, (b = blk>>2, nq = blk&3) ------------
    {
      const int b = blk >> 2, nq = blk & 3;
      if (wave == 0){
        float m0_ = fmaxf(fmaxf(emax_g[b*4+0], emax_g[b*4+1]), fmaxf(emax_g[b*4+2], emax_g[b*4+3]));
        float Z = 0.f;
        #pragma unroll
        for (int sgi = 0; sgi < 4; ++sgi) Z += expf(emax_g[b*4+sgi] - m0_) * esum_g[b*4+sgi];
        #pragma unroll
        for (int rep = 0; rep < 2; ++rep){
          int s = rep*64 + lane;
          al_s[s] = expf(e_g[b*SRC + s] - m0_) / Z;
        }
      }
      __syncthreads();
      int n = nq*256 + (tid & 255), sh = tid >> 8;
      const float* ew = encW + ((size_t)(b*SRC + sh*64))*HID + n;
      float a_ = 0.f;
      #pragma unroll 8
      for (int s = 0; s < 64; ++s) a_ += al_s[sh*64 + s] * ew[(size_t)s*HID];
      redp[tid] = a_;
      __syncthreads();
      if (tid < 256){
        int nn = nq*256 + tid;
        float v = redp[tid] + redp[tid + 256] + combh[b*HID + nn];
        v = tanhf(v);
        out[((size_t)t*BATCH + b)*HID + nn] = v;
        Obuf[b*HID + nn] = v;
      }
    }
    grid_barrier(bar, 256);
  }
}

extern "C" void kernel_launch(void* const* d_in, const int* in_sizes, int n_in,
                              void* d_out, int out_size, void* d_ws, size_t ws_size,
                              hipStream_t stream) {
  const int*   tgt        = (const int*)d_in[0];
  const float* enc_hidden = (const float*)d_in[1];
  const int*   enc_mask   = (const int*)d_in[2];
  const float* dih        = (const float*)d_in[3];
  const float* dic        = (const float*)d_in[4];
  const float* emb        = (const float*)d_in[5];
  const float* W_ih       = (const float*)d_in[6];
  const float* W_hh       = (const float*)d_in[7];
  const float* b_ih       = (const float*)d_in[8];
  const float* b_hh       = (const float*)d_in[9];
  const float* W_att      = (const float*)d_in[10];
  const float* W_comb     = (const float*)d_in[11];
  float* out = (float*)d_out;

  float* ws        = (float*)d_ws;
  float* enc_proj  = ws;                          // 8192*1024
  float* encW      = enc_proj + 8388608;          // 8192*1024
  float* pg        = encW + 8388608;              // 8*64*4096 (precompute scratch)
  float* hh_term   = pg + 2097152;                // 64*4096
  float* hbuf      = hh_term + 262144;            // 64*1024
  float* e_g       = hbuf + 65536;                // 64*128
  float* emax_g    = e_g + 8192;                  // 256
  float* esum_g    = emax_g + 256;                // 256
  float* combh     = esum_g + 256;                // 64*1024
  float* Obuf      = combh + 65536;               // 64*1024
  unsigned* bar    = (unsigned*)(Obuf + 65536);   // 4 uints

  // ---- precompute ----
  big_gemm128<<<dim3(8,64), 256, 0, stream>>>(enc_hidden, 2048, W_att, 2048, enc_proj, HID, 2048);
  big_gemm128<<<dim3(8,64), 256, 0, stream>>>(enc_hidden, 2048, W_comb + HID, 3072, encW, HID, 2048);
  skinny_gemm<0><<<dim3(32,8), 256, 0, stream>>>(dih, HID, nullptr, nullptr, W_hh, HID, pg, G4, 128);
  hh_reduce_kernel<<<dim3(512), 512, 0, stream>>>(pg, b_ih, b_hh, hh_term);
  init_kernel<<<dim3(128), 512, 0, stream>>>(Obuf, bar);

  // ---- persistent scan: 1 launch, 64 steps, 3 grid barriers/step ----
  decoder_persistent<<<dim3(256), 512, 0, stream>>>(
      tgt, enc_mask, dic, emb, W_ih, W_comb, hh_term, enc_proj, encW,
      e_g, emax_g, esum_g, combh, hbuf, Obuf, out, bar);
}

// Round 6
// 10176.962 us; speedup vs baseline: 1.2942x; 1.2942x over previous
//
#include <hip/hip_runtime.h>
#include <hip/hip_bf16.h>
#include <math.h>

// Decoder with attention: V=32000 E=512 H=1024 B=64 S=128 T=65 (NT=64 steps)
#define BATCH 64
#define SRC   128
#define HID   1024
#define EMB   512
#define NT    64
#define G4    4096   // 4H

__device__ __forceinline__ float sigmoidf_(float x){ return 1.0f/(1.0f+expf(-x)); }

// ===================== skinny GEMM (precompute hh_term partials) =====================
template<int AMODE>
__launch_bounds__(256, 2)
__global__ void skinny_gemm(const float* __restrict__ A, int lda,
                            const int* __restrict__ toks, const float* __restrict__ emb,
                            const float* __restrict__ W, int ldw,
                            float* __restrict__ partial, int N, int Kchunk){
  const int nc = blockIdx.x;
  const int kc = blockIdx.y;
  const int kbase = kc * Kchunk;
  const int tid = threadIdx.x;
  __shared__ float As[16][68];
  __shared__ float Bs[16][132];
  const int wave = tid >> 6, lane = tid & 63;
  const int lm = lane & 7, ln = lane >> 3;
  const int nwave = nc*128 + wave*32;
  float acc[8][4] = {};
  const int arow = tid >> 2, akc = (tid & 3) * 4;
  for (int k0 = 0; k0 < Kchunk; k0 += 16){
    int kg = kbase + k0 + akc;
    float4 av;
    if (AMODE == 1){
      if (kg < EMB) av = *(const float4*)(emb + (size_t)toks[arow]*EMB + kg);
      else          av = *(const float4*)(A + (size_t)arow*lda + (kg - EMB));
    } else {
      av = *(const float4*)(A + (size_t)arow*lda + kg);
    }
    As[akc+0][arow]=av.x; As[akc+1][arow]=av.y; As[akc+2][arow]=av.z; As[akc+3][arow]=av.w;
    #pragma unroll
    for (int r = 0; r < 2; ++r){
      int idx = tid + r*256;
      int nrow = idx >> 2, bkc = (idx & 3) * 4;
      float4 wv = *(const float4*)(W + (size_t)(nc*128 + nrow)*ldw + kbase + k0 + bkc);
      Bs[bkc+0][nrow]=wv.x; Bs[bkc+1][nrow]=wv.y; Bs[bkc+2][nrow]=wv.z; Bs[bkc+3][nrow]=wv.w;
    }
    __syncthreads();
    #pragma unroll
    for (int k = 0; k < 16; ++k){
      float4 alo = *(const float4*)&As[k][lm*8];
      float4 ahi = *(const float4*)&As[k][lm*8+4];
      float4 b4  = *(const float4*)&Bs[k][wave*32 + ln*4];
      float am[8] = {alo.x,alo.y,alo.z,alo.w,ahi.x,ahi.y,ahi.z,ahi.w};
      float bn[4] = {b4.x,b4.y,b4.z,b4.w};
      #pragma unroll
      for (int i=0;i<8;++i)
        #pragma unroll
        for (int j=0;j<4;++j)
          acc[i][j] += am[i]*bn[j];
    }
    __syncthreads();
  }
  for (int i=0;i<8;++i){
    int m = lm*8+i;
    float4 v = make_float4(acc[i][0],acc[i][1],acc[i][2],acc[i][3]);
    *(float4*)(partial + ((size_t)(kc*64 + m))*N + nwave + ln*4) = v;
  }
}

// ===================== big GEMM 128x128 (precompute enc_proj / encW) =====================
__launch_bounds__(256, 2)
__global__ void big_gemm128(const float* __restrict__ A, int lda,
                            const float* __restrict__ W, int ldw,
                            float* __restrict__ C, int N, int K){
  const int n0 = blockIdx.x * 128;
  const int m0 = blockIdx.y * 128;
  const int tid = threadIdx.x;
  __shared__ float As[16][132];
  __shared__ float Bs[16][132];
  const int wave = tid >> 6, lane = tid & 63;
  const int wm = wave >> 1, wn = wave & 1;
  const int lm = lane & 7, ln = lane >> 3;
  float acc[8][8] = {};
  for (int k0 = 0; k0 < K; k0 += 16){
    #pragma unroll
    for (int r = 0; r < 2; ++r){
      int idx = tid + r*256;
      int row = idx >> 2, kq = (idx & 3) * 4;
      float4 av = *(const float4*)(A + (size_t)(m0+row)*lda + k0 + kq);
      As[kq+0][row]=av.x; As[kq+1][row]=av.y; As[kq+2][row]=av.z; As[kq+3][row]=av.w;
      float4 wv = *(const float4*)(W + (size_t)(n0+row)*ldw + k0 + kq);
      Bs[kq+0][row]=wv.x; Bs[kq+1][row]=wv.y; Bs[kq+2][row]=wv.z; Bs[kq+3][row]=wv.w;
    }
    __syncthreads();
    #pragma unroll
    for (int k = 0; k < 16; ++k){
      float4 a0 = *(const float4*)&As[k][wm*64 + lm*8];
      float4 a1 = *(const float4*)&As[k][wm*64 + lm*8 + 4];
      float4 b0 = *(const float4*)&Bs[k][wn*64 + ln*8];
      float4 b1 = *(const float4*)&Bs[k][wn*64 + ln*8 + 4];
      float am[8] = {a0.x,a0.y,a0.z,a0.w,a1.x,a1.y,a1.z,a1.w};
      float bn[8] = {b0.x,b0.y,b0.z,b0.w,b1.x,b1.y,b1.z,b1.w};
      #pragma unroll
      for (int i=0;i<8;++i)
        #pragma unroll
        for (int j=0;j<8;++j)
          acc[i][j] += am[i]*bn[j];
    }
    __syncthreads();
  }
  for (int i=0;i<8;++i){
    int m = m0 + wm*64 + lm*8 + i;
    float* cp = C + (size_t)m*N + n0 + wn*64 + ln*8;
    *(float4*)cp     = make_float4(acc[i][0],acc[i][1],acc[i][2],acc[i][3]);
    *(float4*)(cp+4) = make_float4(acc[i][4],acc[i][5],acc[i][6],acc[i][7]);
  }
}

__global__ void hh_reduce_kernel(const float* __restrict__ partial,
                                 const float* __restrict__ b_ih, const float* __restrict__ b_hh,
                                 float* __restrict__ hh_term){
  int g = blockIdx.x*512 + threadIdx.x;   // 64*4096
  int n = g & 4095;
  int b = g >> 12;
  float s = b_ih[n] + b_hh[n];
  #pragma unroll
  for (int kc=0; kc<8; ++kc) s += partial[((size_t)(kc*64+b))*G4 + n];
  hh_term[g] = s;
}

__global__ void init_kernel(float* __restrict__ Obuf, unsigned* __restrict__ bar){
  int i = blockIdx.x*512 + threadIdx.x;
  if (i < BATCH*HID) Obuf[i] = 0.f;
  if (i < 4) bar[i] = 0u;
}

// ===================== grid-wide barrier =====================
// Arrival: one RELEASE fence (L2 writeback, once) + RELAXED fetch_add.
// Wait: RELAXED spin (no cache invalidate per iteration!) + s_sleep backoff.
// Exit: one ACQUIRE fence (L1 invalidate, once).
__device__ __forceinline__ void grid_barrier(unsigned* bar, unsigned nblocks){
  __syncthreads();
  if (threadIdx.x == 0){
    __builtin_amdgcn_fence(__ATOMIC_RELEASE, "agent");
    unsigned g = __hip_atomic_load(&bar[1], __ATOMIC_RELAXED, __HIP_MEMORY_SCOPE_AGENT);
    unsigned old = __hip_atomic_fetch_add(&bar[0], 1u, __ATOMIC_RELAXED, __HIP_MEMORY_SCOPE_AGENT);
    if (old == nblocks - 1u){
      __hip_atomic_store(&bar[0], 0u, __ATOMIC_RELAXED, __HIP_MEMORY_SCOPE_AGENT);
      __hip_atomic_store(&bar[1], g + 1u, __ATOMIC_RELAXED, __HIP_MEMORY_SCOPE_AGENT);
    } else {
      while (__hip_atomic_load(&bar[1], __ATOMIC_RELAXED, __HIP_MEMORY_SCOPE_AGENT) == g)
        __builtin_amdgcn_s_sleep(4);
    }
    __builtin_amdgcn_fence(__ATOMIC_ACQUIRE, "agent");
  }
  __syncthreads();
}

// ===================== persistent decoder: all 64 steps, 3 phases/step =====================
__global__ __launch_bounds__(512, 1)
void decoder_persistent(const int* __restrict__ tgt, const int* __restrict__ enc_mask,
                        const float* __restrict__ dic, const float* __restrict__ emb,
                        const float* __restrict__ W_ih, const float* __restrict__ W_comb,
                        const float* __restrict__ hh_term, const float* __restrict__ enc_proj,
                        const float* __restrict__ encW,
                        float* __restrict__ e_g, float* __restrict__ emax_g, float* __restrict__ esum_g,
                        float* __restrict__ combh, float* __restrict__ hbuf,
                        float* __restrict__ Obuf, float* __restrict__ out,
                        unsigned* __restrict__ bar){
  const int blk = blockIdx.x, tid = threadIdx.x;
  const int wave = tid >> 6, lane = tid & 63;
  const int bg = lane >> 2, rg = lane & 3;     // 16 b-groups x 4 r-groups
  const int j0 = blk * 4;

  __shared__ float Wg[1536*16];      // W_ih slice, [k][rr], rr=jj*4+g -> row g*1024+j0+jj
  __shared__ float Wc[1024*4];       // W_comb h-part slice, [k][j] -> row j0+j
  __shared__ float scratch[8704];    // ybar/h chunk [128][68] k-major; also partial buffers
  __shared__ int   toks[64];
  __shared__ float e_loc[32];
  __shared__ float al_s[SRC];
  __shared__ float redp[512];

  // one-time weight loads
  for (int rr = 0; rr < 16; ++rr){
    int row = (rr & 3) * 1024 + j0 + (rr >> 2);
    for (int k = tid; k < 1536; k += 512) Wg[k*16 + rr] = W_ih[(size_t)row*1536 + k];
  }
  for (int j = 0; j < 4; ++j){
    int n = j0 + j;
    for (int k = tid; k < 1024; k += 512) Wc[k*4 + j] = W_comb[(size_t)n*3072 + k];
  }
  __syncthreads();

  for (int t = 0; t < NT; ++t){
    // ---------------- P1: gates (K=1536 over 8 waves x 12 chunks) + LSTM -> h -------------
    if (tid < 64) toks[tid] = tgt[t*BATCH + tid];
    __syncthreads();
    float acc[4][4] = {};
    for (int c = 0; c < 12; ++c){
      {
        int b = tid & 63, kq = tid >> 6;
        #pragma unroll
        for (int i = 0; i < 4; ++i){
          int kg = c*128 + kq*16 + i*4;
          float4 v;
          if (kg < EMB) v = *(const float4*)(emb + (size_t)toks[b]*EMB + kg);
          else          v = *(const float4*)(Obuf + b*HID + (kg - EMB));
          int kb = kq*16 + i*4;
          scratch[(kb+0)*68 + b] = v.x;
          scratch[(kb+1)*68 + b] = v.y;
          scratch[(kb+2)*68 + b] = v.z;
          scratch[(kb+3)*68 + b] = v.w;
        }
      }
      __syncthreads();
      #pragma unroll
      for (int kk = 0; kk < 16; ++kk){
        int k = wave*16 + kk;
        float4 yb = *(const float4*)&scratch[k*68 + bg*4];
        float4 wv = *(const float4*)&Wg[(c*128 + k)*16 + rg*4];
        float ym[4] = {yb.x, yb.y, yb.z, yb.w};
        float wn[4] = {wv.x, wv.y, wv.z, wv.w};
        #pragma unroll
        for (int i = 0; i < 4; ++i)
          #pragma unroll
          for (int j = 0; j < 4; ++j)
            acc[i][j] += ym[i] * wn[j];
      }
      __syncthreads();
    }
    #pragma unroll
    for (int i = 0; i < 4; ++i)
      #pragma unroll
      for (int j = 0; j < 4; ++j)
        scratch[wave*1024 + (rg*4 + j)*64 + bg*4 + i] = acc[i][j];
    __syncthreads();
    if (tid < 256){
      int b = tid & 63, jj = tid >> 6;
      float g4[4];
      #pragma unroll
      for (int g = 0; g < 4; ++g){
        float s = hh_term[b*G4 + g*1024 + j0 + jj];
        #pragma unroll
        for (int w = 0; w < 8; ++w) s += scratch[w*1024 + (jj*4 + g)*64 + b];
        g4[g] = s;
      }
      float c_ = sigmoidf_(g4[1]) * dic[b*HID + j0 + jj] + sigmoidf_(g4[0]) * tanhf(g4[2]);
      hbuf[b*HID + j0 + jj] = sigmoidf_(g4[3]) * tanhf(c_);
    }
    grid_barrier(bar, 256);

    // ---------------- P2a: e partials for (b = blk>>2, sg = blk&3) -----------------------------
    {
      const int b = blk >> 2, sg = blk & 3;
      for (int i = tid; i < HID; i += 512) scratch[i] = hbuf[b*HID + i];
      __syncthreads();
      #pragma unroll
      for (int q = 0; q < 4; ++q){
        int s = sg*32 + wave*4 + q;
        const float* ep = enc_proj + ((size_t)(b*SRC + s))*HID;
        float sum = 0.f;
        #pragma unroll
        for (int m = 0; m < 4; ++m){
          float4 v  = *(const float4*)(ep + m*256 + lane*4);
          float4 hv = *(const float4*)&scratch[m*256 + lane*4];
          sum += v.x*hv.x + v.y*hv.y + v.z*hv.z + v.w*hv.w;
        }
        #pragma unroll
        for (int off = 32; off; off >>= 1) sum += __shfl_down(sum, off);
        if (lane == 0) e_loc[wave*4 + q] = sum;
      }
      __syncthreads();
      if (wave == 0){
        int sl = lane & 31;
        int s = sg*32 + sl;
        bool valid = lane < 32;
        bool msk = valid ? (enc_mask[b*SRC + s] != 0) : true;
        float ev = (valid && !msk) ? e_loc[sl] : -1e30f;
        if (valid) e_g[b*SRC + s] = ev;
        float mv = ev;
        #pragma unroll
        for (int off = 32; off; off >>= 1) mv = fmaxf(mv, __shfl_down(mv, off));
        mv = __shfl(mv, 0);
        float p = (valid && !msk) ? expf(ev - mv) : 0.f;
        float ps = p;
        #pragma unroll
        for (int off = 32; off; off >>= 1) ps += __shfl_down(ps, off);
        if (lane == 0){ emax_g[b*4 + sg] = mv; esum_g[b*4 + sg] = ps; }
      }
      __syncthreads();
    }
    // ---------------- P2b: comb_h for n-cols j0..j0+3, all b (K=1024, 8 chunks) ----------------
    {
      float acc2[4] = {0.f, 0.f, 0.f, 0.f};
      for (int c = 0; c < 8; ++c){
        {
          int b = tid & 63, kq = tid >> 6;
          #pragma unroll
          for (int i = 0; i < 4; ++i){
            int kg = c*128 + kq*16 + i*4;
            float4 v = *(const float4*)(hbuf + b*HID + kg);
            int kb = kq*16 + i*4;
            scratch[(kb+0)*68 + b] = v.x;
            scratch[(kb+1)*68 + b] = v.y;
            scratch[(kb+2)*68 + b] = v.z;
            scratch[(kb+3)*68 + b] = v.w;
          }
        }
        __syncthreads();
        #pragma unroll
        for (int kk = 0; kk < 16; ++kk){
          int k = wave*16 + kk;
          float4 hb = *(const float4*)&scratch[k*68 + bg*4];
          float w  = Wc[(c*128 + k)*4 + rg];
          acc2[0] += hb.x * w; acc2[1] += hb.y * w;
          acc2[2] += hb.z * w; acc2[3] += hb.w * w;
        }
        __syncthreads();
      }
      #pragma unroll
      for (int i = 0; i < 4; ++i)
        scratch[wave*256 + rg*64 + bg*4 + i] = acc2[i];
      __syncthreads();
      if (tid < 256){
        int b = tid & 63, j = tid >> 6;
        float s = 0.f;
        #pragma unroll
        for (int w = 0; w < 8; ++w) s += scratch[w*256 + j*64 + b];
        combh[b*HID + j0 + j] = s;
      }
    }
    grid_barrier(bar, 256);

    // ---------------- P3: softmax + comb_a + tanh + write, (b = blk>>2, nq = blk&3) ------------
    {
      const int b = blk >> 2, nq = blk & 3;
      if (wave == 0){
        float m0_ = fmaxf(fmaxf(emax_g[b*4+0], emax_g[b*4+1]), fmaxf(emax_g[b*4+2], emax_g[b*4+3]));
        float Z = 0.f;
        #pragma unroll
        for (int sgi = 0; sgi < 4; ++sgi) Z += expf(emax_g[b*4+sgi] - m0_) * esum_g[b*4+sgi];
        #pragma unroll
        for (int rep = 0; rep < 2; ++rep){
          int s = rep*64 + lane;
          al_s[s] = expf(e_g[b*SRC + s] - m0_) / Z;
        }
      }
      __syncthreads();
      int n = nq*256 + (tid & 255), sh = tid >> 8;
      const float* ew = encW + ((size_t)(b*SRC + sh*64))*HID + n;
      float a_ = 0.f;
      #pragma unroll 8
      for (int s = 0; s < 64; ++s) a_ += al_s[sh*64 + s] * ew[(size_t)s*HID];
      redp[tid] = a_;
      __syncthreads();
      if (tid < 256){
        int nn = nq*256 + tid;
        float v = redp[tid] + redp[tid + 256] + combh[b*HID + nn];
        v = tanhf(v);
        out[((size_t)t*BATCH + b)*HID + nn] = v;
        Obuf[b*HID + nn] = v;
      }
    }
    grid_barrier(bar, 256);
  }
}

extern "C" void kernel_launch(void* const* d_in, const int* in_sizes, int n_in,
                              void* d_out, int out_size, void* d_ws, size_t ws_size,
                              hipStream_t stream) {
  const int*   tgt        = (const int*)d_in[0];
  const float* enc_hidden = (const float*)d_in[1];
  const int*   enc_mask   = (const int*)d_in[2];
  const float* dih        = (const float*)d_in[3];
  const float* dic        = (const float*)d_in[4];
  const float* emb        = (const float*)d_in[5];
  const float* W_ih       = (const float*)d_in[6];
  const float* W_hh       = (const float*)d_in[7];
  const float* b_ih       = (const float*)d_in[8];
  const float* b_hh       = (const float*)d_in[9];
  const float* W_att      = (const float*)d_in[10];
  const float* W_comb     = (const float*)d_in[11];
  float* out = (float*)d_out;

  float* ws        = (float*)d_ws;
  float* enc_proj  = ws;                          // 8192*1024
  float* encW      = enc_proj + 8388608;          // 8192*1024
  float* pg        = encW + 8388608;              // 8*64*4096 (precompute scratch)
  float* hh_term   = pg + 2097152;                // 64*4096
  float* hbuf      = hh_term + 262144;            // 64*1024
  float* e_g       = hbuf + 65536;                // 64*128
  float* emax_g    = e_g + 8192;                  // 256
  float* esum_g    = emax_g + 256;                // 256
  float* combh     = esum_g + 256;                // 64*1024
  float* Obuf      = combh + 65536;               // 64*1024
  unsigned* bar    = (unsigned*)(Obuf + 65536);   // 4 uints

  // ---- precompute ----
  big_gemm128<<<dim3(8,64), 256, 0, stream>>>(enc_hidden, 2048, W_att, 2048, enc_proj, HID, 2048);
  big_gemm128<<<dim3(8,64), 256, 0, stream>>>(enc_hidden, 2048, W_comb + HID, 3072, encW, HID, 2048);
  skinny_gemm<0><<<dim3(32,8), 256, 0, stream>>>(dih, HID, nullptr, nullptr, W_hh, HID, pg, G4, 128);
  hh_reduce_kernel<<<dim3(512), 512, 0, stream>>>(pg, b_ih, b_hh, hh_term);
  init_kernel<<<dim3(128), 512, 0, stream>>>(Obuf, bar);

  // ---- persistent scan: 1 launch, 64 steps, 3 grid barriers/step ----
  decoder_persistent<<<dim3(256), 512, 0, stream>>>(
      tgt, enc_mask, dic, emb, W_ih, W_comb, hh_term, enc_proj, encW,
      e_g, emax_g, esum_g, combh, hbuf, Obuf, out, bar);
}

// Round 7
// 8093.182 us; speedup vs baseline: 1.6274x; 1.2575x over previous
//
#include <hip/hip_runtime.h>
#include <hip/hip_bf16.h>
#include <math.h>

// Decoder with attention: V=32000 E=512 H=1024 B=64 S=128 T=65 (NT=64 steps)
#define BATCH 64
#define SRC   128
#define HID   1024
#define EMB   512
#define NT    64
#define G4    4096   // 4H

__device__ __forceinline__ float sigmoidf_(float x){ return 1.0f/(1.0f+expf(-x)); }

// ---- write-through (bypass L1/L2 -> MALL) scalar store / load ----
__device__ __forceinline__ void store_wt(float* p, float v){
  asm volatile("global_store_dword %0, %1, off sc0 sc1" :: "v"(p), "v"(v) : "memory");
}
__device__ __forceinline__ float load_bypass(const float* p){
  float v;
  asm volatile("global_load_dword %0, %1, off sc0 sc1\n\ts_waitcnt vmcnt(0)"
               : "=v"(v) : "v"(p) : "memory");
  return v;
}

// ===================== skinny GEMM (precompute hh_term partials) =====================
template<int AMODE>
__launch_bounds__(256, 2)
__global__ void skinny_gemm(const float* __restrict__ A, int lda,
                            const int* __restrict__ toks, const float* __restrict__ emb,
                            const float* __restrict__ W, int ldw,
                            float* __restrict__ partial, int N, int Kchunk){
  const int nc = blockIdx.x;
  const int kc = blockIdx.y;
  const int kbase = kc * Kchunk;
  const int tid = threadIdx.x;
  __shared__ float As[16][68];
  __shared__ float Bs[16][132];
  const int wave = tid >> 6, lane = tid & 63;
  const int lm = lane & 7, ln = lane >> 3;
  const int nwave = nc*128 + wave*32;
  float acc[8][4] = {};
  const int arow = tid >> 2, akc = (tid & 3) * 4;
  for (int k0 = 0; k0 < Kchunk; k0 += 16){
    int kg = kbase + k0 + akc;
    float4 av;
    if (AMODE == 1){
      if (kg < EMB) av = *(const float4*)(emb + (size_t)toks[arow]*EMB + kg);
      else          av = *(const float4*)(A + (size_t)arow*lda + (kg - EMB));
    } else {
      av = *(const float4*)(A + (size_t)arow*lda + kg);
    }
    As[akc+0][arow]=av.x; As[akc+1][arow]=av.y; As[akc+2][arow]=av.z; As[akc+3][arow]=av.w;
    #pragma unroll
    for (int r = 0; r < 2; ++r){
      int idx = tid + r*256;
      int nrow = idx >> 2, bkc = (idx & 3) * 4;
      float4 wv = *(const float4*)(W + (size_t)(nc*128 + nrow)*ldw + kbase + k0 + bkc);
      Bs[bkc+0][nrow]=wv.x; Bs[bkc+1][nrow]=wv.y; Bs[bkc+2][nrow]=wv.z; Bs[bkc+3][nrow]=wv.w;
    }
    __syncthreads();
    #pragma unroll
    for (int k = 0; k < 16; ++k){
      float4 alo = *(const float4*)&As[k][lm*8];
      float4 ahi = *(const float4*)&As[k][lm*8+4];
      float4 b4  = *(const float4*)&Bs[k][wave*32 + ln*4];
      float am[8] = {alo.x,alo.y,alo.z,alo.w,ahi.x,ahi.y,ahi.z,ahi.w};
      float bn[4] = {b4.x,b4.y,b4.z,b4.w};
      #pragma unroll
      for (int i=0;i<8;++i)
        #pragma unroll
        for (int j=0;j<4;++j)
          acc[i][j] += am[i]*bn[j];
    }
    __syncthreads();
  }
  for (int i=0;i<8;++i){
    int m = lm*8+i;
    float4 v = make_float4(acc[i][0],acc[i][1],acc[i][2],acc[i][3]);
    *(float4*)(partial + ((size_t)(kc*64 + m))*N + nwave + ln*4) = v;
  }
}

// ===================== big GEMM 128x128 (precompute enc_proj / encW) =====================
__launch_bounds__(256, 2)
__global__ void big_gemm128(const float* __restrict__ A, int lda,
                            const float* __restrict__ W, int ldw,
                            float* __restrict__ C, int N, int K){
  const int n0 = blockIdx.x * 128;
  const int m0 = blockIdx.y * 128;
  const int tid = threadIdx.x;
  __shared__ float As[16][132];
  __shared__ float Bs[16][132];
  const int wave = tid >> 6, lane = tid & 63;
  const int wm = wave >> 1, wn = wave & 1;
  const int lm = lane & 7, ln = lane >> 3;
  float acc[8][8] = {};
  for (int k0 = 0; k0 < K; k0 += 16){
    #pragma unroll
    for (int r = 0; r < 2; ++r){
      int idx = tid + r*256;
      int row = idx >> 2, kq = (idx & 3) * 4;
      float4 av = *(const float4*)(A + (size_t)(m0+row)*lda + k0 + kq);
      As[kq+0][row]=av.x; As[kq+1][row]=av.y; As[kq+2][row]=av.z; As[kq+3][row]=av.w;
      float4 wv = *(const float4*)(W + (size_t)(n0+row)*ldw + k0 + kq);
      Bs[kq+0][row]=wv.x; Bs[kq+1][row]=wv.y; Bs[kq+2][row]=wv.z; Bs[kq+3][row]=wv.w;
    }
    __syncthreads();
    #pragma unroll
    for (int k = 0; k < 16; ++k){
      float4 a0 = *(const float4*)&As[k][wm*64 + lm*8];
      float4 a1 = *(const float4*)&As[k][wm*64 + lm*8 + 4];
      float4 b0 = *(const float4*)&Bs[k][wn*64 + ln*8];
      float4 b1 = *(const float4*)&Bs[k][wn*64 + ln*8 + 4];
      float am[8] = {a0.x,a0.y,a0.z,a0.w,a1.x,a1.y,a1.z,a1.w};
      float bn[8] = {b0.x,b0.y,b0.z,b0.w,b1.x,b1.y,b1.z,b1.w};
      #pragma unroll
      for (int i=0;i<8;++i)
        #pragma unroll
        for (int j=0;j<8;++j)
          acc[i][j] += am[i]*bn[j];
    }
    __syncthreads();
  }
  for (int i=0;i<8;++i){
    int m = m0 + wm*64 + lm*8 + i;
    float* cp = C + (size_t)m*N + n0 + wn*64 + ln*8;
    *(float4*)cp     = make_float4(acc[i][0],acc[i][1],acc[i][2],acc[i][3]);
    *(float4*)(cp+4) = make_float4(acc[i][4],acc[i][5],acc[i][6],acc[i][7]);
  }
}

__global__ void hh_reduce_kernel(const float* __restrict__ partial,
                                 const float* __restrict__ b_ih, const float* __restrict__ b_hh,
                                 float* __restrict__ hh_term){
  int g = blockIdx.x*512 + threadIdx.x;   // 64*4096
  int n = g & 4095;
  int b = g >> 12;
  float s = b_ih[n] + b_hh[n];
  #pragma unroll
  for (int kc=0; kc<8; ++kc) s += partial[((size_t)(kc*64+b))*G4 + n];
  hh_term[g] = s;
}

__global__ void init_kernel(float* __restrict__ O_ring0, unsigned* __restrict__ bar){
  int i = blockIdx.x*512 + threadIdx.x;
  if (i < BATCH*HID) O_ring0[i] = 0.f;   // O ring slot 0 = zeros
  if (i < 4) bar[i] = 0u;
}

// ===================== fence-free grid barrier =====================
// All cross-phase data goes through MALL (sc0 sc1 stores). vmcnt(0)+syncthreads
// guarantees every wave's write-through stores are globally visible before the
// arrival atomic. NO agent fences -> L2 stays warm for read-only data.
__device__ __forceinline__ void grid_barrier(unsigned* bar){
  asm volatile("s_waitcnt vmcnt(0)" ::: "memory");
  __syncthreads();
  if (threadIdx.x == 0){
    unsigned g = __hip_atomic_load(&bar[1], __ATOMIC_RELAXED, __HIP_MEMORY_SCOPE_AGENT);
    unsigned old = __hip_atomic_fetch_add(&bar[0], 1u, __ATOMIC_RELAXED, __HIP_MEMORY_SCOPE_AGENT);
    if (old == 255u){
      __hip_atomic_store(&bar[0], 0u, __ATOMIC_RELAXED, __HIP_MEMORY_SCOPE_AGENT);
      __hip_atomic_store(&bar[1], g + 1u, __ATOMIC_RELAXED, __HIP_MEMORY_SCOPE_AGENT);
    } else {
      while (__hip_atomic_load(&bar[1], __ATOMIC_RELAXED, __HIP_MEMORY_SCOPE_AGENT) == g)
        __builtin_amdgcn_s_sleep(4);
    }
  }
  __syncthreads();
}

// ===================== persistent decoder: all 64 steps, 3 phases/step =====================
// Ring buffers (one slot per step) let consumers use NORMAL cached reads:
// first-touch addresses can never be stale in any L2, and L2 dedups the
// 32-blocks-per-XCD redundant staging reads.
__global__ __launch_bounds__(512, 1)
void decoder_persistent(const int* __restrict__ tgt, const int* __restrict__ enc_mask,
                        const float* __restrict__ dic, const float* __restrict__ emb,
                        const float* __restrict__ W_ih, const float* __restrict__ W_comb,
                        const float* __restrict__ hh_term, const float* __restrict__ enc_proj,
                        const float* __restrict__ encW,
                        float* __restrict__ e_g, float* __restrict__ combh,
                        float* __restrict__ h_ring, float* __restrict__ O_ring,
                        float* __restrict__ out, unsigned* __restrict__ bar){
  const int blk = blockIdx.x, tid = threadIdx.x;
  const int wave = tid >> 6, lane = tid & 63;
  const int bg = lane >> 2, rg = lane & 3;     // 16 b-groups x 4 r-groups
  const int j0 = blk * 4;

  __shared__ float Wg[1536*16];      // W_ih slice
  __shared__ float Wc[1024*4];       // W_comb h-part slice
  __shared__ float scratch[8704];
  __shared__ int   toks[64];
  __shared__ float e_loc[32];
  __shared__ float al_s[SRC];
  __shared__ float red[SRC];
  __shared__ float redp[512];

  for (int rr = 0; rr < 16; ++rr){
    int row = (rr & 3) * 1024 + j0 + (rr >> 2);
    for (int k = tid; k < 1536; k += 512) Wg[k*16 + rr] = W_ih[(size_t)row*1536 + k];
  }
  for (int j = 0; j < 4; ++j){
    int n = j0 + j;
    for (int k = tid; k < 1024; k += 512) Wc[k*4 + j] = W_comb[(size_t)n*3072 + k];
  }
  __syncthreads();

  for (int t = 0; t < NT; ++t){
    const float* Oprev = O_ring + (size_t)t*(BATCH*HID);
    float*       hcur  = h_ring + (size_t)t*(BATCH*HID);
    float*       Onext = O_ring + (size_t)(t+1)*(BATCH*HID);

    // ---------------- P1: gates (K=1536 over 8 waves x 12 chunks) + LSTM -> h -------------
    if (tid < 64) toks[tid] = tgt[t*BATCH + tid];
    __syncthreads();
    float acc[4][4] = {};
    for (int c = 0; c < 12; ++c){
      {
        int b = tid & 63, kq = tid >> 6;
        #pragma unroll
        for (int i = 0; i < 4; ++i){
          int kg = c*128 + kq*16 + i*4;
          float4 v;
          if (kg < EMB) v = *(const float4*)(emb + (size_t)toks[b]*EMB + kg);
          else          v = *(const float4*)(Oprev + b*HID + (kg - EMB));
          int kb = kq*16 + i*4;
          scratch[(kb+0)*68 + b] = v.x;
          scratch[(kb+1)*68 + b] = v.y;
          scratch[(kb+2)*68 + b] = v.z;
          scratch[(kb+3)*68 + b] = v.w;
        }
      }
      __syncthreads();
      #pragma unroll
      for (int kk = 0; kk < 16; ++kk){
        int k = wave*16 + kk;
        float4 yb = *(const float4*)&scratch[k*68 + bg*4];
        float4 wv = *(const float4*)&Wg[(c*128 + k)*16 + rg*4];
        float ym[4] = {yb.x, yb.y, yb.z, yb.w};
        float wn[4] = {wv.x, wv.y, wv.z, wv.w};
        #pragma unroll
        for (int i = 0; i < 4; ++i)
          #pragma unroll
          for (int j = 0; j < 4; ++j)
            acc[i][j] += ym[i] * wn[j];
      }
      __syncthreads();
    }
    #pragma unroll
    for (int i = 0; i < 4; ++i)
      #pragma unroll
      for (int j = 0; j < 4; ++j)
        scratch[wave*1024 + (rg*4 + j)*64 + bg*4 + i] = acc[i][j];
    __syncthreads();
    if (tid < 256){
      int b = tid & 63, jj = tid >> 6;
      float g4[4];
      #pragma unroll
      for (int g = 0; g < 4; ++g){
        float s = hh_term[b*G4 + g*1024 + j0 + jj];
        #pragma unroll
        for (int w = 0; w < 8; ++w) s += scratch[w*1024 + (jj*4 + g)*64 + b];
        g4[g] = s;
      }
      float c_ = sigmoidf_(g4[1]) * dic[b*HID + j0 + jj] + sigmoidf_(g4[0]) * tanhf(g4[2]);
      store_wt(hcur + b*HID + j0 + jj, sigmoidf_(g4[3]) * tanhf(c_));
    }
    grid_barrier(bar);

    // ---------------- P2a: e for (b = blk>>2, sg = blk&3) -------------------------------
    {
      const int b = blk >> 2, sg = blk & 3;
      for (int i = tid; i < HID; i += 512) scratch[i] = hcur[b*HID + i];
      __syncthreads();
      #pragma unroll
      for (int q = 0; q < 4; ++q){
        int s = sg*32 + wave*4 + q;
        const float* ep = enc_proj + ((size_t)(b*SRC + s))*HID;
        float sum = 0.f;
        #pragma unroll
        for (int m = 0; m < 4; ++m){
          float4 v  = *(const float4*)(ep + m*256 + lane*4);
          float4 hv = *(const float4*)&scratch[m*256 + lane*4];
          sum += v.x*hv.x + v.y*hv.y + v.z*hv.z + v.w*hv.w;
        }
        #pragma unroll
        for (int off = 32; off; off >>= 1) sum += __shfl_down(sum, off);
        if (lane == 0) e_loc[wave*4 + q] = sum;
      }
      __syncthreads();
      if (wave == 0 && lane < 32){
        int s = sg*32 + lane;
        bool msk = (enc_mask[b*SRC + s] != 0);
        float ev = msk ? -1e30f : e_loc[lane];
        store_wt(e_g + b*SRC + s, ev);
      }
      __syncthreads();
    }
    // ---------------- P2b: comb_h for n-cols j0..j0+3, all b (K=1024, 8 chunks) ---------
    {
      float acc2[4] = {0.f, 0.f, 0.f, 0.f};
      for (int c = 0; c < 8; ++c){
        {
          int b = tid & 63, kq = tid >> 6;
          #pragma unroll
          for (int i = 0; i < 4; ++i){
            int kg = c*128 + kq*16 + i*4;
            float4 v = *(const float4*)(hcur + b*HID + kg);
            int kb = kq*16 + i*4;
            scratch[(kb+0)*68 + b] = v.x;
            scratch[(kb+1)*68 + b] = v.y;
            scratch[(kb+2)*68 + b] = v.z;
            scratch[(kb+3)*68 + b] = v.w;
          }
        }
        __syncthreads();
        #pragma unroll
        for (int kk = 0; kk < 16; ++kk){
          int k = wave*16 + kk;
          float4 hb = *(const float4*)&scratch[k*68 + bg*4];
          float w  = Wc[(c*128 + k)*4 + rg];
          acc2[0] += hb.x * w; acc2[1] += hb.y * w;
          acc2[2] += hb.z * w; acc2[3] += hb.w * w;
        }
        __syncthreads();
      }
      #pragma unroll
      for (int i = 0; i < 4; ++i)
        scratch[wave*256 + rg*64 + bg*4 + i] = acc2[i];
      __syncthreads();
      if (tid < 256){
        int b = tid & 63, j = tid >> 6;
        float s = 0.f;
        #pragma unroll
        for (int w = 0; w < 8; ++w) s += scratch[w*256 + j*64 + b];
        store_wt(combh + b*HID + j0 + j, s);
      }
    }
    grid_barrier(bar);

    // ---------------- P3: softmax + comb_a + tanh + write, (b = blk>>2, nq = blk&3) -----
    {
      const int b = blk >> 2, nq = blk & 3;
      float ev = -1e30f;
      if (tid < SRC){
        ev = load_bypass(e_g + b*SRC + tid);
        red[tid] = ev;
      }
      __syncthreads();
      for (int off=64; off>=1; off>>=1){ if (tid<off) red[tid]=fmaxf(red[tid],red[tid+off]); __syncthreads(); }
      float mval = red[0]; __syncthreads();
      float p = (tid<SRC) ? expf(ev-mval) : 0.f;
      if (tid<SRC) red[tid]=p;
      __syncthreads();
      for (int off=64; off>=1; off>>=1){ if (tid<off) red[tid]+=red[tid+off]; __syncthreads(); }
      if (tid<SRC) al_s[tid] = p/red[0];
      __syncthreads();
      int n = nq*256 + (tid & 255), sh = tid >> 8;
      const float* ew = encW + ((size_t)(b*SRC + sh*64))*HID + n;
      float a_ = 0.f;
      #pragma unroll 8
      for (int s = 0; s < 64; ++s) a_ += al_s[sh*64 + s] * ew[(size_t)s*HID];
      redp[tid] = a_;
      __syncthreads();
      if (tid < 256){
        int nn = nq*256 + tid;
        float ch = load_bypass(combh + b*HID + nn);
        float v = tanhf(redp[tid] + redp[tid + 256] + ch);
        out[((size_t)t*BATCH + b)*HID + nn] = v;
        store_wt(Onext + b*HID + nn, v);
      }
    }
    grid_barrier(bar);
  }
}

extern "C" void kernel_launch(void* const* d_in, const int* in_sizes, int n_in,
                              void* d_out, int out_size, void* d_ws, size_t ws_size,
                              hipStream_t stream) {
  const int*   tgt        = (const int*)d_in[0];
  const float* enc_hidden = (const float*)d_in[1];
  const int*   enc_mask   = (const int*)d_in[2];
  const float* dih        = (const float*)d_in[3];
  const float* dic        = (const float*)d_in[4];
  const float* emb        = (const float*)d_in[5];
  const float* W_ih       = (const float*)d_in[6];
  const float* W_hh       = (const float*)d_in[7];
  const float* b_ih       = (const float*)d_in[8];
  const float* b_hh       = (const float*)d_in[9];
  const float* W_att      = (const float*)d_in[10];
  const float* W_comb     = (const float*)d_in[11];
  float* out = (float*)d_out;

  float* ws        = (float*)d_ws;
  float* enc_proj  = ws;                          // 8192*1024           = 8,388,608
  float* encW      = enc_proj + 8388608;          // 8192*1024           = 8,388,608
  float* hh_term   = encW + 8388608;              // 64*4096             =   262,144
  float* O_ring    = hh_term + 262144;            // 65 * 65536          = 4,259,840
  float* h_ring    = O_ring + 4259840;            // 64 * 65536          = 4,194,304
  float* combh     = h_ring + 4194304;            // 64*1024             =    65,536
  float* e_g       = combh + 65536;               // 64*128              =     8,192
  unsigned* bar    = (unsigned*)(e_g + 8192);     // 4
  float* pg        = O_ring;                      // precompute scratch (aliased; used before rings)

  // ---- precompute ----
  big_gemm128<<<dim3(8,64), 256, 0, stream>>>(enc_hidden, 2048, W_att, 2048, enc_proj, HID, 2048);
  big_gemm128<<<dim3(8,64), 256, 0, stream>>>(enc_hidden, 2048, W_comb + HID, 3072, encW, HID, 2048);
  skinny_gemm<0><<<dim3(32,8), 256, 0, stream>>>(dih, HID, nullptr, nullptr, W_hh, HID, pg, G4, 128);
  hh_reduce_kernel<<<dim3(512), 512, 0, stream>>>(pg, b_ih, b_hh, hh_term);
  init_kernel<<<dim3(128), 512, 0, stream>>>(O_ring, bar);   // zero O slot 0 (overwrites pg alias, after hh_reduce)

  // ---- persistent scan: 1 launch, 64 steps, 3 fence-free grid barriers/step ----
  decoder_persistent<<<dim3(256), 512, 0, stream>>>(
      tgt, enc_mask, dic, emb, W_ih, W_comb, hh_term, enc_proj, encW,
      e_g, combh, h_ring, O_ring, out, bar);
}

// Round 8
// 6887.757 us; speedup vs baseline: 1.9123x; 1.1750x over previous
//
#include <hip/hip_runtime.h>
#include <hip/hip_bf16.h>
#include <math.h>

// Decoder with attention: V=32000 E=512 H=1024 B=64 S=128 T=65 (NT=64 steps)
#define BATCH 64
#define SRC   128
#define HID   1024
#define EMB   512
#define NT    64
#define G4    4096   // 4H

typedef unsigned u32x4 __attribute__((ext_vector_type(4)));

__device__ __forceinline__ float sigmoidf_(float x){ return 1.0f/(1.0f+expf(-x)); }

// ---- write-through (bypass L1/L2 -> MALL) stores / loads ----
__device__ __forceinline__ void store_wt(float* p, float v){
  asm volatile("global_store_dword %0, %1, off sc0 sc1" :: "v"(p), "v"(v) : "memory");
}
__device__ __forceinline__ void store_wt_u(unsigned* p, unsigned v){
  asm volatile("global_store_dword %0, %1, off sc0 sc1" :: "v"(p), "v"(v) : "memory");
}
__device__ __forceinline__ float load_bypass(const float* p){
  float v;
  asm volatile("global_load_dword %0, %1, off sc0 sc1\n\ts_waitcnt vmcnt(0)"
               : "=v"(v) : "v"(p) : "memory");
  return v;
}
__device__ __forceinline__ unsigned load_bypass_u(const unsigned* p){
  unsigned v;
  asm volatile("global_load_dword %0, %1, off sc0 sc1\n\ts_waitcnt vmcnt(0)"
               : "=v"(v) : "v"(p) : "memory");
  return v;
}
__device__ __forceinline__ u32x4 load_bypass4_u(const unsigned* p){
  u32x4 v;
  asm volatile("global_load_dwordx4 %0, %1, off sc0 sc1\n\ts_waitcnt vmcnt(0)"
               : "=v"(v) : "v"(p) : "memory");
  return v;
}

// ===================== skinny GEMM (precompute hh_term partials) =====================
template<int AMODE>
__launch_bounds__(256, 2)
__global__ void skinny_gemm(const float* __restrict__ A, int lda,
                            const int* __restrict__ toks, const float* __restrict__ emb,
                            const float* __restrict__ W, int ldw,
                            float* __restrict__ partial, int N, int Kchunk){
  const int nc = blockIdx.x;
  const int kc = blockIdx.y;
  const int kbase = kc * Kchunk;
  const int tid = threadIdx.x;
  __shared__ float As[16][68];
  __shared__ float Bs[16][132];
  const int wave = tid >> 6, lane = tid & 63;
  const int lm = lane & 7, ln = lane >> 3;
  const int nwave = nc*128 + wave*32;
  float acc[8][4] = {};
  const int arow = tid >> 2, akc = (tid & 3) * 4;
  for (int k0 = 0; k0 < Kchunk; k0 += 16){
    int kg = kbase + k0 + akc;
    float4 av;
    if (AMODE == 1){
      if (kg < EMB) av = *(const float4*)(emb + (size_t)toks[arow]*EMB + kg);
      else          av = *(const float4*)(A + (size_t)arow*lda + (kg - EMB));
    } else {
      av = *(const float4*)(A + (size_t)arow*lda + kg);
    }
    As[akc+0][arow]=av.x; As[akc+1][arow]=av.y; As[akc+2][arow]=av.z; As[akc+3][arow]=av.w;
    #pragma unroll
    for (int r = 0; r < 2; ++r){
      int idx = tid + r*256;
      int nrow = idx >> 2, bkc = (idx & 3) * 4;
      float4 wv = *(const float4*)(W + (size_t)(nc*128 + nrow)*ldw + kbase + k0 + bkc);
      Bs[bkc+0][nrow]=wv.x; Bs[bkc+1][nrow]=wv.y; Bs[bkc+2][nrow]=wv.z; Bs[bkc+3][nrow]=wv.w;
    }
    __syncthreads();
    #pragma unroll
    for (int k = 0; k < 16; ++k){
      float4 alo = *(const float4*)&As[k][lm*8];
      float4 ahi = *(const float4*)&As[k][lm*8+4];
      float4 b4  = *(const float4*)&Bs[k][wave*32 + ln*4];
      float am[8] = {alo.x,alo.y,alo.z,alo.w,ahi.x,ahi.y,ahi.z,ahi.w};
      float bn[4] = {b4.x,b4.y,b4.z,b4.w};
      #pragma unroll
      for (int i=0;i<8;++i)
        #pragma unroll
        for (int j=0;j<4;++j)
          acc[i][j] += am[i]*bn[j];
    }
    __syncthreads();
  }
  for (int i=0;i<8;++i){
    int m = lm*8+i;
    float4 v = make_float4(acc[i][0],acc[i][1],acc[i][2],acc[i][3]);
    *(float4*)(partial + ((size_t)(kc*64 + m))*N + nwave + ln*4) = v;
  }
}

// ===================== big GEMM 128x128 (precompute enc_proj / encW) =====================
__launch_bounds__(256, 2)
__global__ void big_gemm128(const float* __restrict__ A, int lda,
                            const float* __restrict__ W, int ldw,
                            float* __restrict__ C, int N, int K){
  const int n0 = blockIdx.x * 128;
  const int m0 = blockIdx.y * 128;
  const int tid = threadIdx.x;
  __shared__ float As[16][132];
  __shared__ float Bs[16][132];
  const int wave = tid >> 6, lane = tid & 63;
  const int wm = wave >> 1, wn = wave & 1;
  const int lm = lane & 7, ln = lane >> 3;
  float acc[8][8] = {};
  for (int k0 = 0; k0 < K; k0 += 16){
    #pragma unroll
    for (int r = 0; r < 2; ++r){
      int idx = tid + r*256;
      int row = idx >> 2, kq = (idx & 3) * 4;
      float4 av = *(const float4*)(A + (size_t)(m0+row)*lda + k0 + kq);
      As[kq+0][row]=av.x; As[kq+1][row]=av.y; As[kq+2][row]=av.z; As[kq+3][row]=av.w;
      float4 wv = *(const float4*)(W + (size_t)(n0+row)*ldw + k0 + kq);
      Bs[kq+0][row]=wv.x; Bs[kq+1][row]=wv.y; Bs[kq+2][row]=wv.z; Bs[kq+3][row]=wv.w;
    }
    __syncthreads();
    #pragma unroll
    for (int k = 0; k < 16; ++k){
      float4 a0 = *(const float4*)&As[k][wm*64 + lm*8];
      float4 a1 = *(const float4*)&As[k][wm*64 + lm*8 + 4];
      float4 b0 = *(const float4*)&Bs[k][wn*64 + ln*8];
      float4 b1 = *(const float4*)&Bs[k][wn*64 + ln*8 + 4];
      float am[8] = {a0.x,a0.y,a0.z,a0.w,a1.x,a1.y,a1.z,a1.w};
      float bn[8] = {b0.x,b0.y,b0.z,b0.w,b1.x,b1.y,b1.z,b1.w};
      #pragma unroll
      for (int i=0;i<8;++i)
        #pragma unroll
        for (int j=0;j<8;++j)
          acc[i][j] += am[i]*bn[j];
    }
    __syncthreads();
  }
  for (int i=0;i<8;++i){
    int m = m0 + wm*64 + lm*8 + i;
    float* cp = C + (size_t)m*N + n0 + wn*64 + ln*8;
    *(float4*)cp     = make_float4(acc[i][0],acc[i][1],acc[i][2],acc[i][3]);
    *(float4*)(cp+4) = make_float4(acc[i][4],acc[i][5],acc[i][6],acc[i][7]);
  }
}

__global__ void hh_reduce_kernel(const float* __restrict__ partial,
                                 const float* __restrict__ b_ih, const float* __restrict__ b_hh,
                                 float* __restrict__ hh_term){
  int g = blockIdx.x*512 + threadIdx.x;   // 64*4096
  int n = g & 4095;
  int b = g >> 12;
  float s = b_ih[n] + b_hh[n];
  #pragma unroll
  for (int kc=0; kc<8; ++kc) s += partial[((size_t)(kc*64+b))*G4 + n];
  hh_term[g] = s;
}

__global__ void init_kernel(float* __restrict__ O_ring0, unsigned* __restrict__ bar){
  int i = blockIdx.x*512 + threadIdx.x;
  if (i < BATCH*HID) O_ring0[i] = 0.f;   // O ring slot 0 = zeros
  if (i < 512) bar[i] = 0u;              // gen (bar[0]) + arrival slots (bar[128..383])
}

// ===================== RMW-free broadcast grid barrier =====================
// Arrival: each block writes generation g to its OWN slot (write-through; no
// same-line RMW serialization). Master (blk 0, wave 0) polls all 256 slots
// with bypass dwordx4 loads, then publishes gen=g. Others spin on read-only
// gen. Generations are monotonic: no resets, no reset races, no fences; L2
// stays warm for all read-only data.
__device__ __forceinline__ void grid_barrier(unsigned* gen, unsigned* arr, unsigned g, int blk){
  asm volatile("s_waitcnt vmcnt(0)" ::: "memory");
  __syncthreads();
  const int tid = threadIdx.x;
  if (blk == 0){
    if (tid == 0) store_wt_u(arr + 0, g);
    if (tid < 64){
      for (;;){
        u32x4 v = load_bypass4_u(arr + tid*4);
        if (v[0] >= g && v[1] >= g && v[2] >= g && v[3] >= g) break;
        __builtin_amdgcn_s_sleep(1);
      }
    }
    __syncthreads();
    if (tid == 0) store_wt_u(gen, g);
  } else {
    if (tid == 0){
      store_wt_u(arr + blk, g);
      while (load_bypass_u(gen) < g) __builtin_amdgcn_s_sleep(2);
    }
    __syncthreads();
  }
}

// ===================== persistent decoder: all 64 steps, 3 phases/step =====================
__global__ __launch_bounds__(512, 1)
void decoder_persistent(const int* __restrict__ tgt, const int* __restrict__ enc_mask,
                        const float* __restrict__ dic, const float* __restrict__ emb,
                        const float* __restrict__ W_ih, const float* __restrict__ W_comb,
                        const float* __restrict__ hh_term, const float* __restrict__ enc_proj,
                        const float* __restrict__ encW,
                        float* __restrict__ e_g, float* __restrict__ combh,
                        float* __restrict__ h_ring, float* __restrict__ O_ring,
                        float* __restrict__ out, unsigned* __restrict__ bar){
  const int blk = blockIdx.x, tid = threadIdx.x;
  const int wave = tid >> 6, lane = tid & 63;
  const int bg = lane >> 2, rg = lane & 3;     // 16 b-groups x 4 r-groups
  const int j0 = blk * 4;
  unsigned* gen = bar;          // own cache line
  unsigned* arr = bar + 128;    // 256 arrival slots

  __shared__ float Wg[1536*16];      // W_ih slice
  __shared__ float Wc[1024*4];       // W_comb h-part slice
  __shared__ float scratch[8704];
  __shared__ int   toks[64];
  __shared__ float e_loc[32];
  __shared__ float al_s[SRC];
  __shared__ float red[SRC];
  __shared__ float redp[512];

  for (int rr = 0; rr < 16; ++rr){
    int row = (rr & 3) * 1024 + j0 + (rr >> 2);
    for (int k = tid; k < 1536; k += 512) Wg[k*16 + rr] = W_ih[(size_t)row*1536 + k];
  }
  for (int j = 0; j < 4; ++j){
    int n = j0 + j;
    for (int k = tid; k < 1024; k += 512) Wc[k*4 + j] = W_comb[(size_t)n*3072 + k];
  }
  __syncthreads();

  unsigned bar_gen = 0;
  for (int t = 0; t < NT; ++t){
    const float* Oprev = O_ring + (size_t)t*(BATCH*HID);
    float*       hcur  = h_ring + (size_t)t*(BATCH*HID);
    float*       Onext = O_ring + (size_t)(t+1)*(BATCH*HID);

    // ---------------- P1: gates (K=1536 over 8 waves x 12 chunks) + LSTM -> h -------------
    if (tid < 64) toks[tid] = tgt[t*BATCH + tid];
    __syncthreads();
    float acc[4][4] = {};
    for (int c = 0; c < 12; ++c){
      {
        int b = tid & 63, kq = tid >> 6;
        #pragma unroll
        for (int i = 0; i < 4; ++i){
          int kg = c*128 + kq*16 + i*4;
          float4 v;
          if (kg < EMB) v = *(const float4*)(emb + (size_t)toks[b]*EMB + kg);
          else          v = *(const float4*)(Oprev + b*HID + (kg - EMB));
          int kb = kq*16 + i*4;
          scratch[(kb+0)*68 + b] = v.x;
          scratch[(kb+1)*68 + b] = v.y;
          scratch[(kb+2)*68 + b] = v.z;
          scratch[(kb+3)*68 + b] = v.w;
        }
      }
      __syncthreads();
      #pragma unroll
      for (int kk = 0; kk < 16; ++kk){
        int k = wave*16 + kk;
        float4 yb = *(const float4*)&scratch[k*68 + bg*4];
        float4 wv = *(const float4*)&Wg[(c*128 + k)*16 + rg*4];
        float ym[4] = {yb.x, yb.y, yb.z, yb.w};
        float wn[4] = {wv.x, wv.y, wv.z, wv.w};
        #pragma unroll
        for (int i = 0; i < 4; ++i)
          #pragma unroll
          for (int j = 0; j < 4; ++j)
            acc[i][j] += ym[i] * wn[j];
      }
      __syncthreads();
    }
    #pragma unroll
    for (int i = 0; i < 4; ++i)
      #pragma unroll
      for (int j = 0; j < 4; ++j)
        scratch[wave*1024 + (rg*4 + j)*64 + bg*4 + i] = acc[i][j];
    __syncthreads();
    if (tid < 256){
      int b = tid & 63, jj = tid >> 6;
      float g4[4];
      #pragma unroll
      for (int g = 0; g < 4; ++g){
        float s = hh_term[b*G4 + g*1024 + j0 + jj];
        #pragma unroll
        for (int w = 0; w < 8; ++w) s += scratch[w*1024 + (jj*4 + g)*64 + b];
        g4[g] = s;
      }
      float c_ = sigmoidf_(g4[1]) * dic[b*HID + j0 + jj] + sigmoidf_(g4[0]) * tanhf(g4[2]);
      store_wt(hcur + b*HID + j0 + jj, sigmoidf_(g4[3]) * tanhf(c_));
    }
    grid_barrier(gen, arr, ++bar_gen, blk);

    // ---------------- P2a: e for (b = blk>>2, sg = blk&3) -------------------------------
    {
      const int b = blk >> 2, sg = blk & 3;
      for (int i = tid; i < HID; i += 512) scratch[i] = hcur[b*HID + i];
      __syncthreads();
      #pragma unroll
      for (int q = 0; q < 4; ++q){
        int s = sg*32 + wave*4 + q;
        const float* ep = enc_proj + ((size_t)(b*SRC + s))*HID;
        float sum = 0.f;
        #pragma unroll
        for (int m = 0; m < 4; ++m){
          float4 v  = *(const float4*)(ep + m*256 + lane*4);
          float4 hv = *(const float4*)&scratch[m*256 + lane*4];
          sum += v.x*hv.x + v.y*hv.y + v.z*hv.z + v.w*hv.w;
        }
        #pragma unroll
        for (int off = 32; off; off >>= 1) sum += __shfl_down(sum, off);
        if (lane == 0) e_loc[wave*4 + q] = sum;
      }
      __syncthreads();
      if (wave == 0 && lane < 32){
        int s = sg*32 + lane;
        bool msk = (enc_mask[b*SRC + s] != 0);
        float ev = msk ? -1e30f : e_loc[lane];
        store_wt(e_g + b*SRC + s, ev);
      }
      __syncthreads();
    }
    // ---------------- P2b: comb_h for n-cols j0..j0+3, all b (K=1024, 8 chunks) ---------
    {
      float acc2[4] = {0.f, 0.f, 0.f, 0.f};
      for (int c = 0; c < 8; ++c){
        {
          int b = tid & 63, kq = tid >> 6;
          #pragma unroll
          for (int i = 0; i < 4; ++i){
            int kg = c*128 + kq*16 + i*4;
            float4 v = *(const float4*)(hcur + b*HID + kg);
            int kb = kq*16 + i*4;
            scratch[(kb+0)*68 + b] = v.x;
            scratch[(kb+1)*68 + b] = v.y;
            scratch[(kb+2)*68 + b] = v.z;
            scratch[(kb+3)*68 + b] = v.w;
          }
        }
        __syncthreads();
        #pragma unroll
        for (int kk = 0; kk < 16; ++kk){
          int k = wave*16 + kk;
          float4 hb = *(const float4*)&scratch[k*68 + bg*4];
          float w  = Wc[(c*128 + k)*4 + rg];
          acc2[0] += hb.x * w; acc2[1] += hb.y * w;
          acc2[2] += hb.z * w; acc2[3] += hb.w * w;
        }
        __syncthreads();
      }
      #pragma unroll
      for (int i = 0; i < 4; ++i)
        scratch[wave*256 + rg*64 + bg*4 + i] = acc2[i];
      __syncthreads();
      if (tid < 256){
        int b = tid & 63, j = tid >> 6;
        float s = 0.f;
        #pragma unroll
        for (int w = 0; w < 8; ++w) s += scratch[w*256 + j*64 + b];
        store_wt(combh + b*HID + j0 + j, s);
      }
    }
    grid_barrier(gen, arr, ++bar_gen, blk);

    // ---------------- P3: softmax + comb_a + tanh + write, (b = blk>>2, nq = blk&3) -----
    {
      const int b = blk >> 2, nq = blk & 3;
      float ev = -1e30f;
      if (tid < SRC){
        ev = load_bypass(e_g + b*SRC + tid);
        red[tid] = ev;
      }
      __syncthreads();
      for (int off=64; off>=1; off>>=1){ if (tid<off) red[tid]=fmaxf(red[tid],red[tid+off]); __syncthreads(); }
      float mval = red[0]; __syncthreads();
      float p = (tid<SRC) ? expf(ev-mval) : 0.f;
      if (tid<SRC) red[tid]=p;
      __syncthreads();
      for (int off=64; off>=1; off>>=1){ if (tid<off) red[tid]+=red[tid+off]; __syncthreads(); }
      if (tid<SRC) al_s[tid] = p/red[0];
      __syncthreads();
      int n = nq*256 + (tid & 255), sh = tid >> 8;
      const float* ew = encW + ((size_t)(b*SRC + sh*64))*HID + n;
      float a_ = 0.f;
      #pragma unroll 8
      for (int s = 0; s < 64; ++s) a_ += al_s[sh*64 + s] * ew[(size_t)s*HID];
      redp[tid] = a_;
      __syncthreads();
      if (tid < 256){
        int nn = nq*256 + tid;
        float ch = load_bypass(combh + b*HID + nn);
        float v = tanhf(redp[tid] + redp[tid + 256] + ch);
        out[((size_t)t*BATCH + b)*HID + nn] = v;
        store_wt(Onext + b*HID + nn, v);
      }
    }
    grid_barrier(gen, arr, ++bar_gen, blk);
  }
}

extern "C" void kernel_launch(void* const* d_in, const int* in_sizes, int n_in,
                              void* d_out, int out_size, void* d_ws, size_t ws_size,
                              hipStream_t stream) {
  const int*   tgt        = (const int*)d_in[0];
  const float* enc_hidden = (const float*)d_in[1];
  const int*   enc_mask   = (const int*)d_in[2];
  const float* dih        = (const float*)d_in[3];
  const float* dic        = (const float*)d_in[4];
  const float* emb        = (const float*)d_in[5];
  const float* W_ih       = (const float*)d_in[6];
  const float* W_hh       = (const float*)d_in[7];
  const float* b_ih       = (const float*)d_in[8];
  const float* b_hh       = (const float*)d_in[9];
  const float* W_att      = (const float*)d_in[10];
  const float* W_comb     = (const float*)d_in[11];
  float* out = (float*)d_out;

  float* ws        = (float*)d_ws;
  float* enc_proj  = ws;                          // 8192*1024           = 8,388,608
  float* encW      = enc_proj + 8388608;          // 8192*1024           = 8,388,608
  float* hh_term   = encW + 8388608;              // 64*4096             =   262,144
  float* O_ring    = hh_term + 262144;            // 65 * 65536          = 4,259,840
  float* h_ring    = O_ring + 4259840;            // 64 * 65536          = 4,194,304
  float* combh     = h_ring + 4194304;            // 64*1024             =    65,536
  float* e_g       = combh + 65536;               // 64*128              =     8,192
  unsigned* bar    = (unsigned*)(e_g + 8192);     // 512 u32: gen + arrival slots
  float* pg        = O_ring;                      // precompute scratch (aliased; used before rings)

  // ---- precompute ----
  big_gemm128<<<dim3(8,64), 256, 0, stream>>>(enc_hidden, 2048, W_att, 2048, enc_proj, HID, 2048);
  big_gemm128<<<dim3(8,64), 256, 0, stream>>>(enc_hidden, 2048, W_comb + HID, 3072, encW, HID, 2048);
  skinny_gemm<0><<<dim3(32,8), 256, 0, stream>>>(dih, HID, nullptr, nullptr, W_hh, HID, pg, G4, 128);
  hh_reduce_kernel<<<dim3(512), 512, 0, stream>>>(pg, b_ih, b_hh, hh_term);
  init_kernel<<<dim3(128), 512, 0, stream>>>(O_ring, bar);   // zero O slot 0 + barrier state

  // ---- persistent scan: 1 launch, 64 steps, 3 broadcast barriers/step ----
  decoder_persistent<<<dim3(256), 512, 0, stream>>>(
      tgt, enc_mask, dic, emb, W_ih, W_comb, hh_term, enc_proj, encW,
      e_g, combh, h_ring, O_ring, out, bar);
}